// Round 8
// baseline (60.241 us; speedup 1.0000x reference)
//
#include <hip/hip_runtime.h>
#include <stdint.h>

// Hadamard transform along channel dim of NCHW fp32 tensor (FWHT_1024 = H_32 (x) H_32).
// x: [32, 1024, 32, 32] fp32; out[b,d,s] = sum_c x[b,c,s] * (-1)^popc(c&d) / 32.
//
// R8 = R6/R7 + hybrid prefetch to fill the pass-1 read-idle hole.
// R6/R7 (47.5us, 90% of copy ceiling, byte-exact traffic): during pass-1
// (~2us/iter of LDS+VALU) no global loads are in flight, because staging can
// only target LDS after pass-2 reads free it. Fix: groups 0-3 of the NEXT
// chunk are loaded to REGISTERS (4 x float4 = 16 VGPRs, live only from pass-1
// to the store phase -- no spill, unlike R2-R4's 32-VGPR-everywhere buffer)
// with loads issued at the top of pass-1; during the store phase they are
// ds_written while global_load_lds fetches groups 4-7 directly. HBM read
// stream now stays busy through pass-1.
//
// vmcnt bookkeeping (instruction counts, per wave):
//   top of iter (it>=1): outstanding = 4 lds-loads (groups 4-7, oldest) + 32
//     stores -> s_waitcnt vmcnt(32) completes the lds-loads, stores in flight.
//   store phase: vmcnt(0) before ds_write (reg-loads must have landed; the
//     only older ops are last iter's stores, long done).
//
// Structure: BLOCK=1024 (16 waves/CU), 128KiB LDS [c][32], GRID=256 persistent,
// ITERS=4, full-128B-line access everywhere, nt stores. No LDS swizzle needed
// (every access exactly 2 lanes/bank; verified SQ_LDS_BANK_CONFLICT == 0).

constexpr int C       = 1024;
constexpr int SPATIAL = 1024;   // 32*32 contiguous innermost
constexpr int S       = 32;     // spatial positions per chunk (128B per channel row)
constexpr int BLOCK   = 1024;
constexpr int ITERS   = 4;
constexpr int GRID    = 256;    // 1 block/CU; 32 batches * 32 chunks / 4 iters

typedef __attribute__((address_space(3))) uint32_t       lds_u32;
typedef const __attribute__((address_space(1))) uint32_t glb_u32;

__global__ __launch_bounds__(BLOCK) void hadamard_fwht_kernel(
    const float* __restrict__ x, float* __restrict__ out)
{
    __shared__ float lds[C * S];   // 128 KiB, layout [c][32]

    const int t = threadIdx.x;
    const int p = blockIdx.x;

    auto src_of = [&](int g) {
        const int b = g >> 5, chunk = g & 31;
        return x + ((size_t)b * C) * SPATIAL + (size_t)chunk * S;
    };

    // Stage groups [k0, k1) of a chunk via direct HBM->LDS (16B/lane, linear).
    auto stage = [&](int g, int k0, int k1) {
        const float* src = src_of(g);
        for (int k = k0; k < k1; ++k) {
            const int idx = (k << 10) + t;       // 16B-unit index
            const int c   = idx >> 3;            // channel row
            const int s4  = t & 7;               // 16B slot within the 128B row
            const float* gp = src + (size_t)c * SPATIAL + (s4 << 2);
            float* lp = &lds[(size_t)((k << 10) + (t & ~63)) << 2];
            __builtin_amdgcn_global_load_lds((glb_u32*)gp, (lds_u32*)lp, 16, 0, 0);
        }
    };

    stage(p, 0, 8);   // full chunk for it = 0

    float v[32];
    float4 r[4];      // register prefetch: groups 0-3 of next chunk
    const int jj = t >> 5;    // pass1: j-role; pass2: i-role
    const int s  = t & 31;
    const float scale = 1.0f / 32.0f;

    for (int it = 0; it < ITERS; ++it) {
        const int g = it * GRID + p;             // strided: 8 whole batches/iteration
        const int b = g >> 5, chunk = g & 31;
        const size_t base = ((size_t)b * C) * SPATIAL + (size_t)chunk * S;
        const bool pf = (it + 1 < ITERS);

        // Wait for THIS chunk's staging; younger stores stay in flight.
        if (it == 0) asm volatile("s_waitcnt vmcnt(0)" ::: "memory");
        else         asm volatile("s_waitcnt vmcnt(32)" ::: "memory");
        __builtin_amdgcn_s_barrier();

        // ---- issue next chunk's groups 0-3 to registers (fills pass-1 hole) ----
        if (pf) {
            const float* nsrc = src_of((it + 1) * GRID + p);
            #pragma unroll
            for (int k = 0; k < 4; ++k) {
                const int idx = (k << 10) + t;
                const int c   = idx >> 3;
                const int s4  = t & 7;
                r[k] = *reinterpret_cast<const float4*>(
                    nsrc + (size_t)c * SPATIAL + (s4 << 2));
            }
        }

        // ---- pass 1: FWHT_32 along i (rows (i<<5)|jj), in place ----
        #pragma unroll
        for (int i = 0; i < 32; ++i)
            v[i] = lds[(((i << 5) | jj) << 5) + s];
        #pragma unroll
        for (int m = 1; m < 32; m <<= 1)
            #pragma unroll
            for (int gg = 0; gg < 32; gg += (m << 1))
                #pragma unroll
                for (int a = gg; a < gg + m; ++a) {
                    const float pp = v[a], q = v[a + m];
                    v[a]     = pp + q;
                    v[a + m] = pp - q;
                }
        #pragma unroll
        for (int i = 0; i < 32; ++i)
            lds[(((i << 5) | jj) << 5) + s] = v[i];

        asm volatile("s_waitcnt lgkmcnt(0)" ::: "memory");
        __builtin_amdgcn_s_barrier();

        // ---- pass 2 read: rows (jj<<5)|j -> whole tile now in registers ----
        #pragma unroll
        for (int j = 0; j < 32; ++j)
            v[j] = lds[(((jj << 5) | j) << 5) + s];

        asm volatile("s_waitcnt lgkmcnt(0)" ::: "memory");
        __builtin_amdgcn_s_barrier();            // all reads landed -> LDS is free

        // ---- commit reg prefetch (groups 0-3) + stage groups 4-7 directly ----
        if (pf) {
            asm volatile("s_waitcnt vmcnt(0)" ::: "memory");  // reg-loads landed
            #pragma unroll
            for (int k = 0; k < 4; ++k)
                *reinterpret_cast<float4*>(&lds[(size_t)((k << 10) + t) << 2]) = r[k];
            stage((it + 1) * GRID + p, 4, 8);
        }

        // ---- butterfly pass 2 + nt store (2 full 128B lines per wave-instr) ----
        #pragma unroll
        for (int m = 1; m < 32; m <<= 1)
            #pragma unroll
            for (int gg = 0; gg < 32; gg += (m << 1))
                #pragma unroll
                for (int a = gg; a < gg + m; ++a) {
                    const float pp = v[a], q = v[a + m];
                    v[a]     = pp + q;
                    v[a + m] = pp - q;
                }

        float* o = out + base + ((size_t)(jj << 5)) * SPATIAL + s;
        #pragma unroll
        for (int j = 0; j < 32; ++j)
            __builtin_nontemporal_store(v[j] * scale, &o[(size_t)j * SPATIAL]);
    }
}

extern "C" void kernel_launch(void* const* d_in, const int* in_sizes, int n_in,
                              void* d_out, int out_size, void* d_ws, size_t ws_size,
                              hipStream_t stream) {
    const float* x = (const float*)d_in[0];
    float* out = (float*)d_out;
    hadamard_fwht_kernel<<<dim3(GRID), dim3(BLOCK), 0, stream>>>(x, out);
}

// Round 9
// 60.051 us; speedup vs baseline: 1.0032x; 1.0032x over previous
//
#include <hip/hip_runtime.h>
#include <stdint.h>

// Hadamard transform along channel dim of NCHW fp32 tensor (FWHT_1024 = H_32 (x) H_32).
// x: [32, 1024, 32, 32] fp32; out[b,d,s] = sum_c x[b,c,s] * (-1)^popc(c&d) / 32.
//
// R9 = R8 with the register-spill fixed.
// R8's hybrid prefetch (groups 0-3 of next chunk to regs during pass-1) spilled:
// compiler budgeted VGPRs for 8 waves/SIMD (ignoring that 128KiB LDS caps us at
// 1 block/CU = 4 waves/SIMD) and dumped r[4] to scratch -> +49MB WRITE/+21MB
// FETCH, 60us. Fix: __launch_bounds__(1024, 4) declares the true occupancy ->
// 128-VGPR budget, r[4] stays resident (peak live ~70).
// Also: s_waitcnt lgkmcnt(0) before the iteration-top barrier (commit-phase
// ds_writes must be cross-wave visible before pass-1 reads; R8 relied on luck).
//
// Structure (R6-R7 base, 47.5us = 90% of copy ceiling): BLOCK=1024 (16 waves/CU),
// single 128KiB LDS tile [c][32], GRID=256 persistent, ITERS=4, all global
// accesses full 128B lines, staging via global_load_lds width-16, counted vmcnt
// keeps stores+prefetch in flight across barriers, nt stores. No LDS swizzle
// needed: every pass access is exactly 2 lanes/bank (free). Verified:
// SQ_LDS_BANK_CONFLICT == 0, traffic byte-exact.

constexpr int C       = 1024;
constexpr int SPATIAL = 1024;   // 32*32 contiguous innermost
constexpr int S       = 32;     // spatial positions per chunk (128B per channel row)
constexpr int BLOCK   = 1024;
constexpr int ITERS   = 4;
constexpr int GRID    = 256;    // 1 block/CU; 32 batches * 32 chunks / 4 iters

typedef __attribute__((address_space(3))) uint32_t       lds_u32;
typedef const __attribute__((address_space(1))) uint32_t glb_u32;

__global__ __launch_bounds__(BLOCK, 4) void hadamard_fwht_kernel(
    const float* __restrict__ x, float* __restrict__ out)
{
    __shared__ float lds[C * S];   // 128 KiB, layout [c][32]

    const int t = threadIdx.x;
    const int p = blockIdx.x;

    auto src_of = [&](int g) {
        const int b = g >> 5, chunk = g & 31;
        return x + ((size_t)b * C) * SPATIAL + (size_t)chunk * S;
    };

    // Stage groups [k0, k1) of a chunk via direct HBM->LDS (16B/lane, linear).
    auto stage = [&](int g, int k0, int k1) {
        const float* src = src_of(g);
        for (int k = k0; k < k1; ++k) {
            const int idx = (k << 10) + t;       // 16B-unit index
            const int c   = idx >> 3;            // channel row
            const int s4  = t & 7;               // 16B slot within the 128B row
            const float* gp = src + (size_t)c * SPATIAL + (s4 << 2);
            float* lp = &lds[(size_t)((k << 10) + (t & ~63)) << 2];
            __builtin_amdgcn_global_load_lds((glb_u32*)gp, (lds_u32*)lp, 16, 0, 0);
        }
    };

    stage(p, 0, 8);   // full chunk for it = 0

    float v[32];
    float4 r[4];      // register prefetch: groups 0-3 of next chunk
    const int jj = t >> 5;    // pass1: j-role; pass2: i-role
    const int s  = t & 31;
    const float scale = 1.0f / 32.0f;

    for (int it = 0; it < ITERS; ++it) {
        const int g = it * GRID + p;             // strided: 8 whole batches/iteration
        const int b = g >> 5, chunk = g & 31;
        const size_t base = ((size_t)b * C) * SPATIAL + (size_t)chunk * S;
        const bool pf = (it + 1 < ITERS);

        // Wait for THIS chunk's staging (4 lds-loads are the oldest outstanding);
        // the 32 younger nt stores stay in flight. lgkmcnt(0): commit-phase
        // ds_writes must be visible across waves after the barrier.
        if (it == 0) asm volatile("s_waitcnt vmcnt(0) lgkmcnt(0)" ::: "memory");
        else         asm volatile("s_waitcnt vmcnt(32) lgkmcnt(0)" ::: "memory");
        __builtin_amdgcn_s_barrier();

        // ---- issue next chunk's groups 0-3 to registers (fills pass-1 hole) ----
        if (pf) {
            const float* nsrc = src_of((it + 1) * GRID + p);
            #pragma unroll
            for (int k = 0; k < 4; ++k) {
                const int idx = (k << 10) + t;
                const int c   = idx >> 3;
                const int s4  = t & 7;
                r[k] = *reinterpret_cast<const float4*>(
                    nsrc + (size_t)c * SPATIAL + (s4 << 2));
            }
        }

        // ---- pass 1: FWHT_32 along i (rows (i<<5)|jj), in place ----
        #pragma unroll
        for (int i = 0; i < 32; ++i)
            v[i] = lds[(((i << 5) | jj) << 5) + s];
        #pragma unroll
        for (int m = 1; m < 32; m <<= 1)
            #pragma unroll
            for (int gg = 0; gg < 32; gg += (m << 1))
                #pragma unroll
                for (int a = gg; a < gg + m; ++a) {
                    const float pp = v[a], q = v[a + m];
                    v[a]     = pp + q;
                    v[a + m] = pp - q;
                }
        #pragma unroll
        for (int i = 0; i < 32; ++i)
            lds[(((i << 5) | jj) << 5) + s] = v[i];

        asm volatile("s_waitcnt lgkmcnt(0)" ::: "memory");
        __builtin_amdgcn_s_barrier();

        // ---- pass 2 read: rows (jj<<5)|j -> whole tile now in registers ----
        #pragma unroll
        for (int j = 0; j < 32; ++j)
            v[j] = lds[(((jj << 5) | j) << 5) + s];

        asm volatile("s_waitcnt lgkmcnt(0)" ::: "memory");
        __builtin_amdgcn_s_barrier();            // all reads landed -> LDS is free

        // ---- commit reg prefetch (groups 0-3) + stage groups 4-7 directly ----
        if (pf) {
            asm volatile("s_waitcnt vmcnt(0)" ::: "memory");  // reg-loads landed
            #pragma unroll
            for (int k = 0; k < 4; ++k)
                *reinterpret_cast<float4*>(&lds[(size_t)((k << 10) + t) << 2]) = r[k];
            stage((it + 1) * GRID + p, 4, 8);
        }

        // ---- butterfly pass 2 + nt store (2 full 128B lines per wave-instr) ----
        #pragma unroll
        for (int m = 1; m < 32; m <<= 1)
            #pragma unroll
            for (int gg = 0; gg < 32; gg += (m << 1))
                #pragma unroll
                for (int a = gg; a < gg + m; ++a) {
                    const float pp = v[a], q = v[a + m];
                    v[a]     = pp + q;
                    v[a + m] = pp - q;
                }

        float* o = out + base + ((size_t)(jj << 5)) * SPATIAL + s;
        #pragma unroll
        for (int j = 0; j < 32; ++j)
            __builtin_nontemporal_store(v[j] * scale, &o[(size_t)j * SPATIAL]);
    }
}

extern "C" void kernel_launch(void* const* d_in, const int* in_sizes, int n_in,
                              void* d_out, int out_size, void* d_ws, size_t ws_size,
                              hipStream_t stream) {
    const float* x = (const float*)d_in[0];
    float* out = (float*)d_out;
    hadamard_fwht_kernel<<<dim3(GRID), dim3(BLOCK), 0, stream>>>(x, out);
}

// Round 10
// 44.803 us; speedup vs baseline: 1.3446x; 1.3403x over previous
//
#include <hip/hip_runtime.h>
#include <stdint.h>

// Hadamard transform along channel dim of NCHW fp32 tensor (FWHT_1024 = H_32 (x) H_32).
// x: [32, 1024, 32, 32] fp32; out[b,d,s] = sum_c x[b,c,s] * (-1)^popc(c&d) / 32.
//
// R10 = R8/R9 with the spill ACTUALLY fixed: named float4 scalars r0-r3 instead
// of float4 r[4]. R8/R9's array went to scratch (rule #20: SROA runs before the
// pragma-unroll unroller, so the array fails scalar replacement regardless of
// VGPR budget -- VGPR_Count stayed 52 while +49MB WRITE/+21MB FETCH of scratch
// traffic appeared). Named scalars with hand-unrolled loads/commits cannot fail
// promotion.
//
// Goal: fill the pass-1 read-idle hole. Per iteration, between the top barrier
// and the LDS-free point (after pass-2 reads), no global reads are in flight
// (staging can only target LDS once pass-2 reads finish). Groups 0-3 of the
// NEXT chunk are loaded to registers at the top of pass-1, committed to LDS via
// ds_write during the store phase, while global_load_lds fetches groups 4-7.
//
// vmcnt bookkeeping (per wave): top of iter (it>=1): outstanding = 4 lds-loads
// (oldest) + 32 nt stores -> vmcnt(32). Commit phase: vmcnt(0) (reg-loads
// landed; older stores long done).
//
// Structure (R6/R7 base, 47.5us = 90% of copy ceiling): BLOCK=1024 (16 waves/CU),
// single 128KiB LDS tile [c][32], GRID=256 persistent, ITERS=4, all global
// accesses full 128B lines, nt stores, no LDS swizzle needed (2 lanes/bank
// everywhere; verified SQ_LDS_BANK_CONFLICT == 0, traffic byte-exact).

constexpr int C       = 1024;
constexpr int SPATIAL = 1024;   // 32*32 contiguous innermost
constexpr int S       = 32;     // spatial positions per chunk (128B per channel row)
constexpr int BLOCK   = 1024;
constexpr int ITERS   = 4;
constexpr int GRID    = 256;    // 1 block/CU; 32 batches * 32 chunks / 4 iters

typedef __attribute__((address_space(3))) uint32_t       lds_u32;
typedef const __attribute__((address_space(1))) uint32_t glb_u32;

__global__ __launch_bounds__(BLOCK, 4) void hadamard_fwht_kernel(
    const float* __restrict__ x, float* __restrict__ out)
{
    __shared__ float lds[C * S];   // 128 KiB, layout [c][32]

    const int t = threadIdx.x;
    const int p = blockIdx.x;

    auto src_of = [&](int g) {
        const int b = g >> 5, chunk = g & 31;
        return x + ((size_t)b * C) * SPATIAL + (size_t)chunk * S;
    };

    // Stage groups [k0, k1) of a chunk via direct HBM->LDS (16B/lane, linear).
    auto stage = [&](int g, int k0, int k1) {
        const float* src = src_of(g);
        for (int k = k0; k < k1; ++k) {
            const int idx = (k << 10) + t;       // 16B-unit index
            const int c   = idx >> 3;            // channel row
            const int s4  = t & 7;               // 16B slot within the 128B row
            const float* gp = src + (size_t)c * SPATIAL + (s4 << 2);
            float* lp = &lds[(size_t)((k << 10) + (t & ~63)) << 2];
            __builtin_amdgcn_global_load_lds((glb_u32*)gp, (lds_u32*)lp, 16, 0, 0);
        }
    };

    stage(p, 0, 8);   // full chunk for it = 0

    float v[32];
    float4 r0, r1, r2, r3;    // named scalars: cannot fail SROA -> stay in VGPRs
    const int jj = t >> 5;    // pass1: j-role; pass2: i-role
    const int s  = t & 31;
    const int s4 = t & 7;     // 16B slot within a 128B row (prefetch addressing)
    const float scale = 1.0f / 32.0f;

    for (int it = 0; it < ITERS; ++it) {
        const int g = it * GRID + p;             // strided: 8 whole batches/iteration
        const int b = g >> 5, chunk = g & 31;
        const size_t base = ((size_t)b * C) * SPATIAL + (size_t)chunk * S;
        const bool pf = (it + 1 < ITERS);

        // Wait for THIS chunk's staging (oldest outstanding); younger nt stores
        // stay in flight. lgkmcnt(0): commit-phase ds_writes must be cross-wave
        // visible after the barrier.
        if (it == 0) asm volatile("s_waitcnt vmcnt(0) lgkmcnt(0)" ::: "memory");
        else         asm volatile("s_waitcnt vmcnt(32) lgkmcnt(0)" ::: "memory");
        __builtin_amdgcn_s_barrier();

        // ---- issue next chunk's groups 0-3 to registers (fills pass-1 hole) ----
        if (pf) {
            const float* nsrc = src_of((it + 1) * GRID + p);
            r0 = *reinterpret_cast<const float4*>(nsrc + (size_t)(((0 << 10) + t) >> 3) * SPATIAL + (s4 << 2));
            r1 = *reinterpret_cast<const float4*>(nsrc + (size_t)(((1 << 10) + t) >> 3) * SPATIAL + (s4 << 2));
            r2 = *reinterpret_cast<const float4*>(nsrc + (size_t)(((2 << 10) + t) >> 3) * SPATIAL + (s4 << 2));
            r3 = *reinterpret_cast<const float4*>(nsrc + (size_t)(((3 << 10) + t) >> 3) * SPATIAL + (s4 << 2));
        }

        // ---- pass 1: FWHT_32 along i (rows (i<<5)|jj), in place ----
        #pragma unroll
        for (int i = 0; i < 32; ++i)
            v[i] = lds[(((i << 5) | jj) << 5) + s];
        #pragma unroll
        for (int m = 1; m < 32; m <<= 1)
            #pragma unroll
            for (int gg = 0; gg < 32; gg += (m << 1))
                #pragma unroll
                for (int a = gg; a < gg + m; ++a) {
                    const float pp = v[a], q = v[a + m];
                    v[a]     = pp + q;
                    v[a + m] = pp - q;
                }
        #pragma unroll
        for (int i = 0; i < 32; ++i)
            lds[(((i << 5) | jj) << 5) + s] = v[i];

        asm volatile("s_waitcnt lgkmcnt(0)" ::: "memory");
        __builtin_amdgcn_s_barrier();

        // ---- pass 2 read: rows (jj<<5)|j -> whole tile now in registers ----
        #pragma unroll
        for (int j = 0; j < 32; ++j)
            v[j] = lds[(((jj << 5) | j) << 5) + s];

        asm volatile("s_waitcnt lgkmcnt(0)" ::: "memory");
        __builtin_amdgcn_s_barrier();            // all reads landed -> LDS is free

        // ---- commit reg prefetch (groups 0-3) + stage groups 4-7 directly ----
        if (pf) {
            asm volatile("s_waitcnt vmcnt(0)" ::: "memory");  // reg-loads landed
            *reinterpret_cast<float4*>(&lds[(size_t)((0 << 10) + t) << 2]) = r0;
            *reinterpret_cast<float4*>(&lds[(size_t)((1 << 10) + t) << 2]) = r1;
            *reinterpret_cast<float4*>(&lds[(size_t)((2 << 10) + t) << 2]) = r2;
            *reinterpret_cast<float4*>(&lds[(size_t)((3 << 10) + t) << 2]) = r3;
            stage((it + 1) * GRID + p, 4, 8);
        }

        // ---- butterfly pass 2 + nt store (2 full 128B lines per wave-instr) ----
        #pragma unroll
        for (int m = 1; m < 32; m <<= 1)
            #pragma unroll
            for (int gg = 0; gg < 32; gg += (m << 1))
                #pragma unroll
                for (int a = gg; a < gg + m; ++a) {
                    const float pp = v[a], q = v[a + m];
                    v[a]     = pp + q;
                    v[a + m] = pp - q;
                }

        float* o = out + base + ((size_t)(jj << 5)) * SPATIAL + s;
        #pragma unroll
        for (int j = 0; j < 32; ++j)
            __builtin_nontemporal_store(v[j] * scale, &o[(size_t)j * SPATIAL]);
    }
}

extern "C" void kernel_launch(void* const* d_in, const int* in_sizes, int n_in,
                              void* d_out, int out_size, void* d_ws, size_t ws_size,
                              hipStream_t stream) {
    const float* x = (const float*)d_in[0];
    float* out = (float*)d_out;
    hadamard_fwht_kernel<<<dim3(GRID), dim3(BLOCK), 0, stream>>>(x, out);
}